// Round 7
// baseline (286.350 us; speedup 1.0000x reference)
//
#include <hip/hip_runtime.h>
#include <hip/hip_bf16.h>

#define NB 2
#define NS 2048
#define NE 1024
#define NH 16
#define ND 64
#define MTOT (NB * NS)   // 4096

// Q pre-scale: 1/sqrt(64) * log2(e)  -> softmax in exp2 domain
#define QSCALE 0.18033688011112042f

typedef __attribute__((ext_vector_type(8))) short bf8_t;
typedef __attribute__((ext_vector_type(4))) short bf4_t;
typedef __attribute__((ext_vector_type(4))) float f32x4;
typedef __attribute__((ext_vector_type(16))) float f32x16;

__device__ __forceinline__ short f2bf(float f) {
    union { float f; unsigned u; } v; v.f = f;
    return (short)((v.u + 0x7FFFu + ((v.u >> 16) & 1u)) >> 16);
}
__device__ __forceinline__ float bflo(unsigned u) {
    union { unsigned u; float f; } v; v.u = u << 16;
    return v.f;
}
__device__ __forceinline__ float bfhi(unsigned u) {
    union { unsigned u; float f; } v; v.u = u & 0xFFFF0000u;
    return v.f;
}
__device__ __forceinline__ unsigned cvtpk(float lo, float hi) {
    unsigned r;
    asm("v_cvt_pk_bf16_f32 %0, %1, %2" : "=v"(r) : "v"(lo), "v"(hi));
    return r;
}
__device__ __forceinline__ bf8_t mk4(unsigned a, unsigned b, unsigned c, unsigned d) {
    union { unsigned u[4]; bf8_t v; } t;
    t.u[0] = a; t.u[1] = b; t.u[2] = c; t.u[3] = d;
    return t.v;
}

// async global->LDS, 16B per lane; LDS dest must be linear (base + lane*16)
#define GLOAD16(g, l) __builtin_amdgcn_global_load_lds( \
    (const __attribute__((address_space(1))) void*)(g), \
    (__attribute__((address_space(3))) void*)(l), 16, 0, 0)

// ---------------- Kernel B: weight transpose + bf16 cast ----------------
// W[p][h][e][d] fp32 -> wt[p][n=h*64+d][e] bf16 (B^T, [N][K]).
__global__ __launch_bounds__(256) void wt_kernel(
    const float* __restrict__ Wq, const float* __restrict__ Wk, const float* __restrict__ Wv,
    short* __restrict__ wt)
{
    const int p = blockIdx.x / NH, h = blockIdx.x % NH;
    const int e0 = blockIdx.y * 64;
    const float* W = (p == 0) ? Wq : (p == 1) ? Wk : Wv;
    const int t = threadIdx.x;
    const int er = t >> 2, dc = (t & 3) * 16;
    const float* src = W + ((size_t)h * NE + e0 + er) * ND + dc;
    short* dst = wt + (size_t)(p * NH + h) * ND * NE;
#pragma unroll
    for (int j = 0; j < 16; j += 4) {
        float4 x = *(const float4*)(src + j);
        dst[(size_t)(dc + j + 0) * NE + e0 + er] = f2bf(x.x);
        dst[(size_t)(dc + j + 1) * NE + e0 + er] = f2bf(x.y);
        dst[(size_t)(dc + j + 2) * NE + e0 + er] = f2bf(x.z);
        dst[(size_t)(dc + j + 3) * NE + e0 + er] = f2bf(x.w);
    }
}

// ---------------- Kernel C: fused conv+projection GEMM ----------------
// A fp32 -> reg -> cvt_pk -> bf16 LDS (m97 linear layout); B bf16 via global_load_lds.
// 128x128 tile, BK=32, 4 waves. grid (32, 8, 3): z = p.
// p0: Q [b][h][s][d] * QSCALE; p1: K [b][h][s][d]; p2: V^T [b][h][d][s].
__global__ __launch_bounds__(256) void proj_kernel(
    const float* __restrict__ query, const float* __restrict__ key_in, const float* __restrict__ value_in,
    const short* __restrict__ wt,
    const float* __restrict__ bq, const float* __restrict__ bk, const float* __restrict__ bv,
    short* __restrict__ q_ws, short* __restrict__ k_ws, short* __restrict__ vT_ws)
{
    __shared__ __attribute__((aligned(16))) short As[128 * 32];   // 8 KB
    __shared__ __attribute__((aligned(16))) short Bs[128 * 32];   // 8 KB

    const int p = blockIdx.z;
    const float* A = (p == 0) ? query : (p == 1) ? key_in : value_in;
    const short* Bm = wt + (size_t)p * NE * NE;
    const float* bias_all = (p == 0) ? bq : (p == 1) ? bk : bv;
    const float oscale = (p == 0) ? QSCALE : 1.0f;

    const int m0 = blockIdx.x * 128, n0 = blockIdx.y * 128;
    const int t = threadIdx.x, lane = t & 63, w = t >> 6;
    const int l15 = lane & 15, g = lane >> 4, g8 = g * 8;
    const int wr = w >> 1, wc = w & 1;

    // A staging: one half-row (16 fp32) per thread per K-step
    const int arow = t >> 1, ac = (t & 1) * 16;
    const float* ag = A + (size_t)(m0 + arow) * NE + ac;
    short* awr = &As[arow * 32 + ac];
    // B staging: 2 x 16B via global_load_lds (linear dest)
    const short* bg = Bm + (size_t)(n0 + (t >> 2)) * NE + (t & 3) * 8;
    short* bsl = Bs + t * 8;

    f32x4 acc[4][4];
#pragma unroll
    for (int i = 0; i < 4; ++i)
#pragma unroll
        for (int j = 0; j < 4; ++j) acc[i][j] = (f32x4){0.f, 0.f, 0.f, 0.f};

    for (int k0 = 0; k0 < NE; k0 += 32) {
        // issue fp32 A loads before the barrier (overlap with prior compute)
        const float4 x0 = *(const float4*)(ag + k0);
        const float4 x1 = *(const float4*)(ag + k0 + 4);
        const float4 x2 = *(const float4*)(ag + k0 + 8);
        const float4 x3 = *(const float4*)(ag + k0 + 12);
        __syncthreads();
        GLOAD16(bg + k0, bsl);
        GLOAD16(bg + k0 + (size_t)64 * NE, bsl + 2048);
        *(bf8_t*)awr = mk4(cvtpk(x0.x, x0.y), cvtpk(x0.z, x0.w),
                           cvtpk(x1.x, x1.y), cvtpk(x1.z, x1.w));
        *(bf8_t*)(awr + 8) = mk4(cvtpk(x2.x, x2.y), cvtpk(x2.z, x2.w),
                                 cvtpk(x3.x, x3.y), cvtpk(x3.z, x3.w));
        __syncthreads();

        bf8_t af[4], bfr[4];
#pragma unroll
        for (int mf = 0; mf < 4; ++mf)
            af[mf] = *(const bf8_t*)&As[(wr * 64 + mf * 16 + l15) * 32 + g8];
#pragma unroll
        for (int nf = 0; nf < 4; ++nf)
            bfr[nf] = *(const bf8_t*)&Bs[(wc * 64 + nf * 16 + l15) * 32 + g8];
#pragma unroll
        for (int mf = 0; mf < 4; ++mf)
#pragma unroll
            for (int nf = 0; nf < 4; ++nf)
                acc[mf][nf] = __builtin_amdgcn_mfma_f32_16x16x32_bf16(af[mf], bfr[nf], acc[mf][nf], 0, 0, 0);
    }

    const int h = (n0 + wc * 64) >> 6;
    const float* bias = bias_all + h * ND;

    if (p < 2) {
        short* outp = (p == 0) ? q_ws : k_ws;
#pragma unroll
        for (int mf = 0; mf < 4; ++mf) {
            const int m = m0 + wr * 64 + mf * 16 + g * 4;
            const int bb = m >> 11, s = m & (NS - 1);
#pragma unroll
            for (int nf = 0; nf < 4; ++nf) {
                const int d = nf * 16 + l15;
                const float bi = bias[d];
                short* op = outp + (((size_t)bb * NH + h) * NS + s) * ND + d;
#pragma unroll
                for (int r = 0; r < 4; ++r)
                    op[(size_t)r * ND] = f2bf((acc[mf][nf][r] + bi) * oscale);
            }
        }
    } else {
#pragma unroll
        for (int mf = 0; mf < 4; ++mf) {
            const int m = m0 + wr * 64 + mf * 16 + g * 4;
            const int bb = m >> 11, s = m & (NS - 1);
#pragma unroll
            for (int nf = 0; nf < 4; ++nf) {
                const int d = nf * 16 + l15;
                const float bi = bias[d];
                bf4_t pk;
#pragma unroll
                for (int r = 0; r < 4; ++r) pk[r] = f2bf(acc[mf][nf][r] + bi);
                *(bf4_t*)&vT_ws[(((size_t)bb * NH + h) * ND + d) * NS + s] = pk;
            }
        }
    }
}

// ---------------- Kernel D: causal flash attention, in-block split-KV ----------------
// One block = (q-tile of 32 rows, bh). 4 warps interleave KV tiles (tt = w, w+4, ...),
// partials combined through LDS. grid 2048 x 256, heavy-first. O fp32 [B,S,E].
__global__ __launch_bounds__(256) void attn_kernel(
    const short* __restrict__ q_ws, const short* __restrict__ k_ws,
    const short* __restrict__ vT_ws, float* __restrict__ O)
{
    __shared__ float cm[4][32], cl[4][32];
    __shared__ __attribute__((aligned(16))) unsigned oP[4][32][36];  // packed bf16x2 O^T

    const int t = threadIdx.x, lane = t & 63, w = t >> 6;
    const int jj = (int)blockIdx.x;
    const int jq = 63 - (jj >> 5);             // heavy-first
    const int bh = jj & 31;
    const int b = bh >> 4, h = bh & 15;
    const int q0w = jq * 32;
    const int ntot = (jq >> 1) + 1;            // 64-wide KV tiles
    const int l31 = lane & 31, hi = lane >> 5;
    const size_t base = (size_t)bh * NS * ND;

    // Q B-frags (pre-scaled): lane holds Q[q=l31][d=16s+8*hi+j]
    bf8_t Qf[4];
    {
        const short* qsrc = q_ws + base + (size_t)(q0w + l31) * ND + hi * 8;
#pragma unroll
        for (int s = 0; s < 4; ++s) Qf[s] = *(const bf8_t*)(qsrc + s * 16);
    }

    f32x16 Oa[2];
#pragma unroll
    for (int rb = 0; rb < 2; ++rb)
#pragma unroll
        for (int r = 0; r < 16; ++r) Oa[rb][r] = 0.f;
    float m_i = -1e30f, l_i = 0.f;
    const int qg = q0w + l31;

    for (int tt = w; tt < ntot; tt += 4) {
        const int t0 = tt * 64;

        bf8_t Kf[2][4];
#pragma unroll
        for (int c = 0; c < 2; ++c) {
            const short* kp = k_ws + base + (size_t)(t0 + c * 32 + l31) * ND + hi * 8;
#pragma unroll
            for (int s = 0; s < 4; ++s) Kf[c][s] = *(const bf8_t*)(kp + s * 16);
        }
        bf8_t Vf[4][2];
#pragma unroll
        for (int rb = 0; rb < 2; ++rb) {
            const short* vp = vT_ws + base + (size_t)(rb * 32 + l31) * NS + t0 + hi * 8;
#pragma unroll
            for (int cs = 0; cs < 4; ++cs) Vf[cs][rb] = *(const bf8_t*)(vp + cs * 16);
        }

        // S^T = K Q^T (log2 domain)
        f32x16 Sv[2];
#pragma unroll
        for (int c = 0; c < 2; ++c) {
#pragma unroll
            for (int r = 0; r < 16; ++r) Sv[c][r] = 0.f;
#pragma unroll
            for (int s = 0; s < 4; ++s)
                Sv[c] = __builtin_amdgcn_mfma_f32_32x32x16_bf16(Kf[c][s], Qf[s], Sv[c], 0, 0, 0);
        }

        if (tt == ntot - 1) {   // only the last tile straddles the diagonal
#pragma unroll
            for (int c = 0; c < 2; ++c)
#pragma unroll
                for (int r = 0; r < 16; ++r) {
                    const int kvg = t0 + c * 32 + (r & 3) + 8 * (r >> 2) + 4 * hi;
                    if (kvg > qg) Sv[c][r] = -1e30f;
                }
        }

        float mloc = Sv[0][0];
#pragma unroll
        for (int r = 1; r < 16; ++r) mloc = fmaxf(mloc, Sv[0][r]);
#pragma unroll
        for (int r = 0; r < 16; ++r) mloc = fmaxf(mloc, Sv[1][r]);
        mloc = fmaxf(mloc, __shfl_xor(mloc, 32));

        if (__any(mloc > m_i + 11.0f)) {   // defer-max (T13)
            const float mn = fmaxf(m_i, mloc);
            const float al = exp2f(m_i - mn);
            m_i = mn;
            l_i *= al;
#pragma unroll
            for (int rb = 0; rb < 2; ++rb)
#pragma unroll
                for (int r = 0; r < 16; ++r) Oa[rb][r] *= al;
        }

        float rs = 0.f;
        bf8_t Pf[2][2];
#pragma unroll
        for (int c = 0; c < 2; ++c) {
#pragma unroll
            for (int r = 0; r < 16; ++r) {
                const float pv = exp2f(Sv[c][r] - m_i);
                Sv[c][r] = pv;
                rs += pv;
            }
            unsigned wv[8], xv[8];
#pragma unroll
            for (int i = 0; i < 8; ++i) wv[i] = cvtpk(Sv[c][2 * i], Sv[c][2 * i + 1]);
#pragma unroll
            for (int i = 0; i < 8; ++i) xv[i] = __shfl_xor(wv[i], 32);
            Pf[c][0] = hi ? mk4(xv[2], xv[3], wv[2], wv[3]) : mk4(wv[0], wv[1], xv[0], xv[1]);
            Pf[c][1] = hi ? mk4(xv[6], xv[7], wv[6], wv[7]) : mk4(wv[4], wv[5], xv[4], xv[5]);
        }
        rs += __shfl_xor(rs, 32);
        l_i += rs;

        // O^T += V^T P^T
#pragma unroll
        for (int cs = 0; cs < 4; ++cs)
#pragma unroll
            for (int rb = 0; rb < 2; ++rb)
                Oa[rb] = __builtin_amdgcn_mfma_f32_32x32x16_bf16(Vf[cs][rb], Pf[cs >> 1][cs & 1], Oa[rb], 0, 0, 0);
    }

    // ---- in-block combine ----
    if (hi == 0) { cm[w][l31] = m_i; cl[w][l31] = l_i; }
    // pack unnormalized partial O^T into LDS as bf16x2
#pragma unroll
    for (int rb = 0; rb < 2; ++rb)
#pragma unroll
        for (int q4 = 0; q4 < 4; ++q4) {
            const int dp = rb * 16 + 4 * q4 + 2 * hi;
            oP[w][l31][dp]     = cvtpk(Oa[rb][q4 * 4 + 0], Oa[rb][q4 * 4 + 1]);
            oP[w][l31][dp + 1] = cvtpk(Oa[rb][q4 * 4 + 2], Oa[rb][q4 * 4 + 3]);
        }
    __syncthreads();

    // combine + normalize + store: thread t owns (q = t>>3, 8 d values)
    {
        const int q = t >> 3, dp0 = (t & 7) * 4;
        float wgt[4];
        float mfin = fmaxf(fmaxf(cm[0][q], cm[1][q]), fmaxf(cm[2][q], cm[3][q]));
        float lfin = 0.f;
#pragma unroll
        for (int ww = 0; ww < 4; ++ww) {
            const float e = exp2f(cm[ww][q] - mfin);
            lfin += e * cl[ww][q];
            wgt[ww] = e;
        }
        const float inv = 1.0f / lfin;
#pragma unroll
        for (int ww = 0; ww < 4; ++ww) wgt[ww] *= inv;

        float o[8];
#pragma unroll
        for (int j = 0; j < 8; ++j) o[j] = 0.f;
#pragma unroll
        for (int ww = 0; ww < 4; ++ww) {
            const uint4 u = *(const uint4*)&oP[ww][q][dp0];
            o[0] += wgt[ww] * bflo(u.x); o[1] += wgt[ww] * bfhi(u.x);
            o[2] += wgt[ww] * bflo(u.y); o[3] += wgt[ww] * bfhi(u.y);
            o[4] += wgt[ww] * bflo(u.z); o[5] += wgt[ww] * bfhi(u.z);
            o[6] += wgt[ww] * bflo(u.w); o[7] += wgt[ww] * bfhi(u.w);
        }
        float* op = O + ((size_t)b * NS + q0w + q) * NE + h * 64 + dp0 * 2;
        *(float4*)op = (float4){o[0], o[1], o[2], o[3]};
        *(float4*)(op + 4) = (float4){o[4], o[5], o[6], o[7]};
    }
}

// ---------------- Kernel E: residual + custom LayerNorm ----------------
__global__ __launch_bounds__(256) void ln_kernel(
    const float* __restrict__ Oin, const float* __restrict__ resid,
    const float* __restrict__ ln_scale, const float* __restrict__ ln_shift,
    float* __restrict__ out)
{
    __shared__ float red[8];
    const int row = blockIdx.x, t = threadIdx.x;
    const size_t basei = (size_t)row * NE + t * 4;
    float4 x = *(const float4*)(Oin + basei);
    float4 rr = *(const float4*)(resid + basei);
    x.x += rr.x; x.y += rr.y; x.z += rr.z; x.w += rr.w;
    float ps = x.x + x.y + x.z + x.w;
#pragma unroll
    for (int off = 32; off; off >>= 1) ps += __shfl_xor(ps, off);
    if ((t & 63) == 0) red[t >> 6] = ps;
    __syncthreads();
    const float mean = (red[0] + red[1] + red[2] + red[3]) * (1.0f / NE);
    const float dx0 = x.x - mean, dx1 = x.y - mean, dx2 = x.z - mean, dx3 = x.w - mean;
    float ss = dx0 * dx0 + dx1 * dx1 + dx2 * dx2 + dx3 * dx3;
#pragma unroll
    for (int off = 32; off; off >>= 1) ss += __shfl_xor(ss, off);
    if ((t & 63) == 0) red[4 + (t >> 6)] = ss;
    __syncthreads();
    const float stdv = sqrtf((red[4] + red[5] + red[6] + red[7]) * (1.0f / (NE - 1)));
    float4 sc = *(const float4*)(ln_scale + t * 4);
    float4 sh = *(const float4*)(ln_shift + t * 4);
    float4 o;
    o.x = sc.x * dx0 / (stdv + 1e-6f + sh.x);
    o.y = sc.y * dx1 / (stdv + 1e-6f + sh.y);
    o.z = sc.z * dx2 / (stdv + 1e-6f + sh.z);
    o.w = sc.w * dx3 / (stdv + 1e-6f + sh.w);
    *(float4*)(out + basei) = o;
}

extern "C" void kernel_launch(void* const* d_in, const int* in_sizes, int n_in,
                              void* d_out, int out_size, void* d_ws, size_t ws_size,
                              hipStream_t stream) {
    (void)in_sizes; (void)n_in; (void)out_size; (void)ws_size;
    const float* query    = (const float*)d_in[0];
    const float* key_in   = (const float*)d_in[1];
    const float* value_in = (const float*)d_in[2];
    const float* resid    = (const float*)d_in[3];
    const float* Wq = (const float*)d_in[4];
    const float* bq = (const float*)d_in[5];
    const float* Wk = (const float*)d_in[6];
    const float* bk = (const float*)d_in[7];
    const float* Wv = (const float*)d_in[8];
    const float* bv = (const float*)d_in[9];
    const float* ln_scale = (const float*)d_in[10];
    const float* ln_shift = (const float*)d_in[11];
    float* out = (float*)d_out;

    // workspace (peak 46 MB, proven):
    //   wt [0,6)  q [6,14)  k [14,22)  vT [22,30)  O [30,46) fp32
    char* ws = (char*)d_ws;
    short* wt_ws = (short*)ws;
    short* q_ws  = (short*)(ws + (6u << 20));
    short* k_ws  = (short*)(ws + (14u << 20));
    short* vT_ws = (short*)(ws + (22u << 20));
    float* O_ws  = (float*)(ws + (30u << 20));

    wt_kernel<<<dim3(3 * NH, NE / 64), 256, 0, stream>>>(Wq, Wk, Wv, wt_ws);
    proj_kernel<<<dim3(MTOT / 128, NE / 128, 3), 256, 0, stream>>>(
        query, key_in, value_in, wt_ws, bq, bk, bv, q_ws, k_ws, vT_ws);
    attn_kernel<<<2048, 256, 0, stream>>>(q_ws, k_ws, vT_ws, O_ws);
    ln_kernel<<<dim3(NB * NS), 256, 0, stream>>>(O_ws, resid, ln_scale, ln_shift, out);
}

// Round 10
// 241.855 us; speedup vs baseline: 1.1840x; 1.1840x over previous
//
#include <hip/hip_runtime.h>
#include <hip/hip_bf16.h>

#define NB 2
#define NS 2048
#define NE 1024
#define NH 16
#define ND 64
#define MTOT (NB * NS)   // 4096

// Q pre-scale: 1/sqrt(64) * log2(e)  -> softmax in exp2 domain
#define QSCALE 0.18033688011112042f

typedef __attribute__((ext_vector_type(8))) short bf8_t;
typedef __attribute__((ext_vector_type(4))) short bf4_t;
typedef __attribute__((ext_vector_type(4))) float f32x4;
typedef __attribute__((ext_vector_type(16))) float f32x16;

__device__ __forceinline__ short f2bf(float f) {
    union { float f; unsigned u; } v; v.f = f;
    return (short)((v.u + 0x7FFFu + ((v.u >> 16) & 1u)) >> 16);
}
__device__ __forceinline__ unsigned cvtpk(float lo, float hi) {
    unsigned r;
    asm("v_cvt_pk_bf16_f32 %0, %1, %2" : "=v"(r) : "v"(lo), "v"(hi));
    return r;
}
__device__ __forceinline__ bf8_t mk4(unsigned a, unsigned b, unsigned c, unsigned d) {
    union { unsigned u[4]; bf8_t v; } t;
    t.u[0] = a; t.u[1] = b; t.u[2] = c; t.u[3] = d;
    return t.v;
}

// async global->LDS, 16B per lane; LDS dest linear (wave base + lane*16)
#define GLOAD16(g, l) __builtin_amdgcn_global_load_lds( \
    (const __attribute__((address_space(1))) void*)(g), \
    (__attribute__((address_space(3))) void*)(l), 16, 0, 0)

// ---------------- Kernel A: prep = wt transpose (blocks 0..767) + conv (768..2047) ----------------
// wt: W[p][h][e][d] fp32 -> wt[p][n=h*64+d][e] bf16, via LDS transpose (coalesced stores).
// conv: query/key/value fp32 -> in_bf[3][4096][1024] bf16.
__global__ __launch_bounds__(256) void prep_kernel(
    const float* __restrict__ query, const float* __restrict__ key_in, const float* __restrict__ value_in,
    const float* __restrict__ Wq, const float* __restrict__ Wk, const float* __restrict__ Wv,
    short* __restrict__ wt, short* __restrict__ in_bf)
{
    __shared__ float T[64][68];
    const int bid = (int)blockIdx.x, t = threadIdx.x;
    if (bid < 768) {
        const int hb = bid >> 4;                 // 0..47
        const int p = hb >> 4, h = hb & 15;
        const int e0 = (bid & 15) << 6;
        const float* W = (p == 0) ? Wq : (p == 1) ? Wk : Wv;
        const int er = t >> 2, dc = (t & 3) * 16;
        const float* src = W + ((size_t)h * NE + e0 + er) * ND + dc;
#pragma unroll
        for (int j = 0; j < 16; j += 4) {
            float4 x = *(const float4*)(src + j);
            T[er][dc + j + 0] = x.x; T[er][dc + j + 1] = x.y;
            T[er][dc + j + 2] = x.z; T[er][dc + j + 3] = x.w;
        }
        __syncthreads();
        const int dr = t >> 2, ec = (t & 3) * 16;
        float v[16];
#pragma unroll
        for (int j = 0; j < 16; ++j) v[j] = T[ec + j][dr];
        short* dst = wt + (size_t)p * NE * NE + (size_t)(h * 64 + dr) * NE + e0 + ec;
        *(bf8_t*)dst = mk4(cvtpk(v[0], v[1]), cvtpk(v[2], v[3]),
                           cvtpk(v[4], v[5]), cvtpk(v[6], v[7]));
        *(bf8_t*)(dst + 8) = mk4(cvtpk(v[8], v[9]), cvtpk(v[10], v[11]),
                                 cvtpk(v[12], v[13]), cvtpk(v[14], v[15]));
    } else {
        const size_t nchunk = (size_t)3 * MTOT * NE / 8;
        const size_t stride = (size_t)1280 * 256;
        for (size_t i = (size_t)(bid - 768) * 256 + t; i < nchunk; i += stride) {
            size_t e = i * 8;
            int p = (int)(e >> 22);
            const float* src = (p == 0) ? query : (p == 1) ? key_in : value_in;
            size_t off = e & ((1ull << 22) - 1);
            float4 x0 = *(const float4*)(src + off);
            float4 x1 = *(const float4*)(src + off + 4);
            *(bf8_t*)(in_bf + e) = mk4(cvtpk(x0.x, x0.y), cvtpk(x0.z, x0.w),
                                       cvtpk(x1.x, x1.y), cvtpk(x1.z, x1.w));
        }
    }
}

// ---------------- Kernel C: projection GEMM (pure m97 structure) ----------------
// 128x128 tile, BK=32, 4 waves, global_load_lds both operands. grid (32, 8, 3).
// p0: Q [b][h][s][d] * QSCALE; p1: K [b][h][s][d]; p2: V^T [b][h][d][s].
__global__ __launch_bounds__(256) void proj_kernel(
    const short* __restrict__ in_bf, const short* __restrict__ wt,
    const float* __restrict__ bq, const float* __restrict__ bk, const float* __restrict__ bv,
    short* __restrict__ q_ws, short* __restrict__ k_ws, short* __restrict__ vT_ws)
{
    __shared__ __attribute__((aligned(16))) short As[128 * 32];
    __shared__ __attribute__((aligned(16))) short Bs[128 * 32];

    const int p = blockIdx.z;
    const short* A = in_bf + (size_t)p * MTOT * NE;
    const short* Bm = wt + (size_t)p * NE * NE;
    const float* bias_all = (p == 0) ? bq : (p == 1) ? bk : bv;
    const float oscale = (p == 0) ? QSCALE : 1.0f;

    const int m0 = blockIdx.x * 128, n0 = blockIdx.y * 128;
    const int t = threadIdx.x, lane = t & 63, w = t >> 6;
    const int l15 = lane & 15, g = lane >> 4, g8 = g * 8;
    const int wr = w >> 1, wc = w & 1;

    const int srow = t >> 2, scol = (t & 3) * 8;
    const short* ag = A + (size_t)(m0 + srow) * NE + scol;
    const short* bg = Bm + (size_t)(n0 + srow) * NE + scol;
    short* asl = As + t * 8;
    short* bsl = Bs + t * 8;

    f32x4 acc[4][4];
#pragma unroll
    for (int i = 0; i < 4; ++i)
#pragma unroll
        for (int j = 0; j < 4; ++j) acc[i][j] = (f32x4){0.f, 0.f, 0.f, 0.f};

    for (int k0 = 0; k0 < NE; k0 += 32) {
        __syncthreads();
        GLOAD16(ag + k0, asl);
        GLOAD16(ag + k0 + (size_t)64 * NE, asl + 2048);
        GLOAD16(bg + k0, bsl);
        GLOAD16(bg + k0 + (size_t)64 * NE, bsl + 2048);
        __syncthreads();
        bf8_t af[4], bfr[4];
#pragma unroll
        for (int mf = 0; mf < 4; ++mf)
            af[mf] = *(const bf8_t*)&As[(wr * 64 + mf * 16 + l15) * 32 + g8];
#pragma unroll
        for (int nf = 0; nf < 4; ++nf)
            bfr[nf] = *(const bf8_t*)&Bs[(wc * 64 + nf * 16 + l15) * 32 + g8];
#pragma unroll
        for (int mf = 0; mf < 4; ++mf)
#pragma unroll
            for (int nf = 0; nf < 4; ++nf)
                acc[mf][nf] = __builtin_amdgcn_mfma_f32_16x16x32_bf16(af[mf], bfr[nf], acc[mf][nf], 0, 0, 0);
    }

    const int h = (n0 + wc * 64) >> 6;
    const float* bias = bias_all + h * ND;

    if (p < 2) {
        short* outp = (p == 0) ? q_ws : k_ws;
#pragma unroll
        for (int mf = 0; mf < 4; ++mf) {
            const int m = m0 + wr * 64 + mf * 16 + g * 4;
            const int bb = m >> 11, s = m & (NS - 1);
#pragma unroll
            for (int nf = 0; nf < 4; ++nf) {
                const int d = nf * 16 + l15;
                const float bi = bias[d];
                short* op = outp + (((size_t)bb * NH + h) * NS + s) * ND + d;
#pragma unroll
                for (int r = 0; r < 4; ++r)
                    op[(size_t)r * ND] = f2bf((acc[mf][nf][r] + bi) * oscale);
            }
        }
    } else {
#pragma unroll
        for (int mf = 0; mf < 4; ++mf) {
            const int m = m0 + wr * 64 + mf * 16 + g * 4;
            const int bb = m >> 11, s = m & (NS - 1);
#pragma unroll
            for (int nf = 0; nf < 4; ++nf) {
                const int d = nf * 16 + l15;
                const float bi = bias[d];
                bf4_t pk;
#pragma unroll
                for (int r = 0; r < 4; ++r) pk[r] = f2bf(acc[mf][nf][r] + bi);
                *(bf4_t*)&vT_ws[(((size_t)bb * NH + h) * ND + d) * NS + s] = pk;
            }
        }
    }
}

// ---------------- Kernel D: causal flash attention, LDS-shared KV ----------------
// Block = (bh, 4 consecutive q-tiles). Warp w owns q-tile 4a+w (32 rows).
// KV tiles staged once/block via global_load_lds (XOR-pre-swizzled source),
// double-buffered, counted vmcnt + raw barriers. XCD-partitioned: 4 bh per XCD.
__global__ __launch_bounds__(256) void attn_kernel(
    const short* __restrict__ q_ws, const short* __restrict__ k_ws,
    const short* __restrict__ vT_ws, float* __restrict__ O)
{
    __shared__ __attribute__((aligned(16))) short KV[2][2][64 * 64];  // 32 KB [buf][K/V]

    const int t = threadIdx.x, lane = t & 63, w = t >> 6;
    const int xcd = (int)blockIdx.x & 7, idx = (int)blockIdx.x >> 3;
    const int a = 15 - (idx >> 2);             // heavy-first within XCD
    const int bh = xcd * 4 + (idx & 3);        // 4 bh per XCD -> KV L2-resident
    const int b = bh >> 4, h = bh & 15;
    const int jq = 4 * a + w;
    const int q0w = jq * 32;
    const int ntw = (jq >> 1) + 1;             // this warp's KV tiles
    const int maxnt = 2 * a + 2;               // block max (warp 3)
    const int l31 = lane & 31, hi = lane >> 5;
    const size_t base = (size_t)bh * NS * ND;
    const int qg = q0w + l31;

    // staging addresses: row r1 = t>>3, col pre-swizzled (involution with read-side XOR)
    const int r1 = t >> 3;
    const int cswz = ((t & 7) * 8) ^ ((r1 & 7) << 3);   // shorts
    const short* kgb = k_ws + base + (size_t)r1 * ND + cswz;        // + (t0+{0,32})*ND
    const short* vgb = vT_ws + base + (size_t)r1 * NS + cswz;       // + t0 + {0,32}*NS

#define STAGE(c, t0) do { \
    GLOAD16(kgb + (size_t)(t0) * ND, &KV[c][0][t * 8]); \
    GLOAD16(kgb + (size_t)((t0) + 32) * ND, &KV[c][0][2048 + t * 8]); \
    GLOAD16(vgb + (t0), &KV[c][1][t * 8]); \
    GLOAD16(vgb + (size_t)32 * NS + (t0), &KV[c][1][2048 + t * 8]); \
} while (0)

    // Q B-frags (pre-scaled): lane holds Q[q=l31][d=16s+8*hi+j]
    bf8_t Qf[4];
    {
        const short* qsrc = q_ws + base + (size_t)(q0w + l31) * ND + hi * 8;
#pragma unroll
        for (int s = 0; s < 4; ++s) Qf[s] = *(const bf8_t*)(qsrc + s * 16);
    }

    f32x16 Oa[2];
#pragma unroll
    for (int rb = 0; rb < 2; ++rb)
#pragma unroll
        for (int r = 0; r < 16; ++r) Oa[rb][r] = 0.f;
    float m_i = -1e30f, l_i = 0.f;
    const int sw = (l31 & 7) << 3;             // read-side XOR (shorts)

    STAGE(0, 0);

    for (int tt = 0; tt < maxnt; ++tt) {
        const int cur = tt & 1;
        if (tt + 1 < maxnt) {
            STAGE(cur ^ 1, (tt + 1) * 64);
            asm volatile("s_waitcnt vmcnt(4)" ::: "memory");
        } else {
            asm volatile("s_waitcnt vmcnt(0)" ::: "memory");
        }
        __builtin_amdgcn_sched_barrier(0);
        __builtin_amdgcn_s_barrier();
        __builtin_amdgcn_sched_barrier(0);

        if (tt < ntw) {
            const int t0 = tt * 64;
            // K A-frags from LDS (swizzled)
            bf8_t Kf[2][4];
#pragma unroll
            for (int c = 0; c < 2; ++c)
#pragma unroll
                for (int s = 0; s < 4; ++s)
                    Kf[c][s] = *(const bf8_t*)&KV[cur][0][(c * 32 + l31) * 64 + ((s * 16 + hi * 8) ^ sw)];

            // S^T = K Q^T (log2 domain)
            f32x16 Sv[2];
#pragma unroll
            for (int c = 0; c < 2; ++c) {
#pragma unroll
                for (int r = 0; r < 16; ++r) Sv[c][r] = 0.f;
#pragma unroll
                for (int s = 0; s < 4; ++s)
                    Sv[c] = __builtin_amdgcn_mfma_f32_32x32x16_bf16(Kf[c][s], Qf[s], Sv[c], 0, 0, 0);
            }

            if (tt == ntw - 1) {
#pragma unroll
                for (int c = 0; c < 2; ++c)
#pragma unroll
                    for (int r = 0; r < 16; ++r) {
                        const int kvg = t0 + c * 32 + (r & 3) + 8 * (r >> 2) + 4 * hi;
                        if (kvg > qg) Sv[c][r] = -1e30f;
                    }
            }

            float mloc = Sv[0][0];
#pragma unroll
            for (int r = 1; r < 16; ++r) mloc = fmaxf(mloc, Sv[0][r]);
#pragma unroll
            for (int r = 0; r < 16; ++r) mloc = fmaxf(mloc, Sv[1][r]);
            mloc = fmaxf(mloc, __shfl_xor(mloc, 32));

            if (__any(mloc > m_i + 11.0f)) {   // defer-max (T13)
                const float mn = fmaxf(m_i, mloc);
                const float al = exp2f(m_i - mn);
                m_i = mn;
                l_i *= al;
#pragma unroll
                for (int rb = 0; rb < 2; ++rb)
#pragma unroll
                    for (int r = 0; r < 16; ++r) Oa[rb][r] *= al;
            }

            float rs = 0.f;
            bf8_t Pf[2][2];
#pragma unroll
            for (int c = 0; c < 2; ++c) {
#pragma unroll
                for (int r = 0; r < 16; ++r) {
                    const float pv = exp2f(Sv[c][r] - m_i);
                    Sv[c][r] = pv;
                    rs += pv;
                }
                unsigned wv[8], xv[8];
#pragma unroll
                for (int i = 0; i < 8; ++i) wv[i] = cvtpk(Sv[c][2 * i], Sv[c][2 * i + 1]);
#pragma unroll
                for (int i = 0; i < 8; ++i) xv[i] = __shfl_xor(wv[i], 32);
                Pf[c][0] = hi ? mk4(xv[2], xv[3], wv[2], wv[3]) : mk4(wv[0], wv[1], xv[0], xv[1]);
                Pf[c][1] = hi ? mk4(xv[6], xv[7], wv[6], wv[7]) : mk4(wv[4], wv[5], xv[4], xv[5]);
            }
            rs += __shfl_xor(rs, 32);
            l_i += rs;

            // O^T += V^T P^T (V^T frags read late to cut VGPR pressure)
#pragma unroll
            for (int cs = 0; cs < 4; ++cs) {
#pragma unroll
                for (int rb = 0; rb < 2; ++rb) {
                    const bf8_t vf = *(const bf8_t*)&KV[cur][1][(rb * 32 + l31) * 64 + ((cs * 16 + hi * 8) ^ sw)];
                    Oa[rb] = __builtin_amdgcn_mfma_f32_32x32x16_bf16(vf, Pf[cs >> 1][cs & 1], Oa[rb], 0, 0, 0);
                }
            }
        }
        __builtin_amdgcn_sched_barrier(0);
        __builtin_amdgcn_s_barrier();          // protect cur before next-iter restage
        __builtin_amdgcn_sched_barrier(0);
    }

    __syncthreads();   // full drain before LDS reuse

    // epilogue: per-warp transpose in reused LDS, normalized fp32 stores
    float* oTw = (float*)(&KV[0][0][0]) + w * (32 * 36);
    const float inv = 1.0f / l_i;
#pragma unroll
    for (int rb = 0; rb < 2; ++rb) {
#pragma unroll
        for (int r = 0; r < 16; ++r) {
            const int crow = (r & 3) + 8 * (r >> 2) + 4 * hi;
            oTw[l31 * 36 + crow] = Oa[rb][r] * inv;
        }
        asm volatile("s_waitcnt lgkmcnt(0)" ::: "memory");
        __builtin_amdgcn_sched_barrier(0);
        const float* src = &oTw[l31 * 36 + hi * 16];
        float4 a0 = *(const float4*)(src);
        float4 a1 = *(const float4*)(src + 4);
        float4 a2 = *(const float4*)(src + 8);
        float4 a3 = *(const float4*)(src + 12);
        float* op = O + ((size_t)b * NS + q0w + l31) * NE + h * 64 + rb * 32 + hi * 16;
        *(float4*)op = a0;
        *(float4*)(op + 4) = a1;
        *(float4*)(op + 8) = a2;
        *(float4*)(op + 12) = a3;
        asm volatile("s_waitcnt lgkmcnt(0)" ::: "memory");
        __builtin_amdgcn_sched_barrier(0);
    }
#undef STAGE
}

// ---------------- Kernel E: residual + custom LayerNorm ----------------
__global__ __launch_bounds__(256) void ln_kernel(
    const float* __restrict__ Oin, const float* __restrict__ resid,
    const float* __restrict__ ln_scale, const float* __restrict__ ln_shift,
    float* __restrict__ out)
{
    __shared__ float red[8];
    const int row = blockIdx.x, t = threadIdx.x;
    const size_t basei = (size_t)row * NE + t * 4;
    float4 x = *(const float4*)(Oin + basei);
    float4 rr = *(const float4*)(resid + basei);
    x.x += rr.x; x.y += rr.y; x.z += rr.z; x.w += rr.w;
    float ps = x.x + x.y + x.z + x.w;
#pragma unroll
    for (int off = 32; off; off >>= 1) ps += __shfl_xor(ps, off);
    if ((t & 63) == 0) red[t >> 6] = ps;
    __syncthreads();
    const float mean = (red[0] + red[1] + red[2] + red[3]) * (1.0f / NE);
    const float dx0 = x.x - mean, dx1 = x.y - mean, dx2 = x.z - mean, dx3 = x.w - mean;
    float ss = dx0 * dx0 + dx1 * dx1 + dx2 * dx2 + dx3 * dx3;
#pragma unroll
    for (int off = 32; off; off >>= 1) ss += __shfl_xor(ss, off);
    if ((t & 63) == 0) red[4 + (t >> 6)] = ss;
    __syncthreads();
    const float stdv = sqrtf((red[4] + red[5] + red[6] + red[7]) * (1.0f / (NE - 1)));
    float4 sc = *(const float4*)(ln_scale + t * 4);
    float4 sh = *(const float4*)(ln_shift + t * 4);
    float4 o;
    o.x = sc.x * dx0 / (stdv + 1e-6f + sh.x);
    o.y = sc.y * dx1 / (stdv + 1e-6f + sh.y);
    o.z = sc.z * dx2 / (stdv + 1e-6f + sh.z);
    o.w = sc.w * dx3 / (stdv + 1e-6f + sh.w);
    *(float4*)(out + basei) = o;
}

extern "C" void kernel_launch(void* const* d_in, const int* in_sizes, int n_in,
                              void* d_out, int out_size, void* d_ws, size_t ws_size,
                              hipStream_t stream) {
    (void)in_sizes; (void)n_in; (void)out_size; (void)ws_size;
    const float* query    = (const float*)d_in[0];
    const float* key_in   = (const float*)d_in[1];
    const float* value_in = (const float*)d_in[2];
    const float* resid    = (const float*)d_in[3];
    const float* Wq = (const float*)d_in[4];
    const float* bq = (const float*)d_in[5];
    const float* Wk = (const float*)d_in[6];
    const float* bk = (const float*)d_in[7];
    const float* Wv = (const float*)d_in[8];
    const float* bv = (const float*)d_in[9];
    const float* ln_scale = (const float*)d_in[10];
    const float* ln_shift = (const float*)d_in[11];
    float* out = (float*)d_out;

    // workspace (peak 54 MB, proven in round 1):
    //   in_bf [0,24)   wt [24,30)   q [30,38)  k [38,46)  vT [46,54)
    //   O fp32 [0,16) aliases in_bf (dead after proj)
    char* ws = (char*)d_ws;
    short* in_bf = (short*)ws;
    short* wt_ws = (short*)(ws + (24u << 20));
    short* q_ws  = (short*)(ws + (30u << 20));
    short* k_ws  = (short*)(ws + (38u << 20));
    short* vT_ws = (short*)(ws + (46u << 20));
    float* O_ws  = (float*)ws;

    prep_kernel<<<2048, 256, 0, stream>>>(query, key_in, value_in, Wq, Wk, Wv, wt_ws, in_bf);
    proj_kernel<<<dim3(MTOT / 128, NE / 128, 3), 256, 0, stream>>>(
        in_bf, wt_ws, bq, bk, bv, q_ws, k_ws, vT_ws);
    attn_kernel<<<512, 256, 0, stream>>>(q_ws, k_ws, vT_ws, O_ws);
    ln_kernel<<<dim3(NB * NS), 256, 0, stream>>>(O_ws, resid, ln_scale, ln_shift, out);
}